// Round 5
// baseline (132.063 us; speedup 1.0000x reference)
//
#include <hip/hip_runtime.h>

// EdgeEmbedding: B=8, L=256, A=15, K=9, EDGE_SIZE=16 — single fused kernel.
//
// Output layout (all float32, concatenated flat):
//   [0,      30720)  block_id   = i/15
//   [30720,  32768)  batch_id   = i/256
//   [32768, 106496)  edges [2][36864]   (row0 src, row1 dst; intra then inter)
//   [106496,696320)  edge_attr [36864][16]
//
// Precision strategy (round-4 post-mortem): the oracle is f64; full-f64 is
// 4-cyc/op and latency-bound. We compute candidate min-d^2 in f32 (error
// <= ~5e-4 abs), take the 9th-smallest f32 value v9 per mask class, mark
// candidates with d2f32 <= v9 + DELTA (DELTA=0.02 >> 2*f32err, so the f64
// top-9 is provably a subset of the marked set), refine ONLY marked
// candidates in f64 (one candidate per wave, lanes split the 225 atom
// pairs), and run the ordered top-9 selection on refined f64 values.
// Ordering is identical to the all-f64 round-4 kernel (f64 noise ~1e-13 vs
// candidate gaps >~1e-10), which passed with absmax 37.

#define BB   8
#define LL   256
#define AA   15
#define KK   9

#define O_BATCH   30720
#define O_EDGES   32768
#define NE_HALF   18432   // B*L*K
#define NE        36864
#define O_ATTR    106496
#define N_ATTR    589824  // NE*16
#define DELTA     0.02f

__global__ __launch_bounds__(256) void edge_fused_kernel(
    const float* __restrict__ pos,   // [B,L,A,3] f32
    const int*   __restrict__ frag,  // [B,L]
    const float* __restrict__ emb,   // [2,16]
    float*       __restrict__ out)
{
    const int blk = blockIdx.x;      // = b*256 + i
    const int b   = blk >> 8;
    const int i   = blk & 255;
    const int j   = threadIdx.x;     // candidate dst block

    __shared__ float  sAi[45];       // row-i atom coords (f32)
    __shared__ float  sX2i[AA];      // row-i per-atom |x|^2 (f32)
    __shared__ float  sD32[LL];      // f32 min-d^2 per candidate
    __shared__ int    sSeg[LL];
    __shared__ double sD64[LL];      // refined f64 min-d^2 (INF if unmarked)
    __shared__ int    sList[LL];     // marked candidate list
    __shared__ int    sCnt;
    __shared__ float  sV9[2];        // 9th-smallest f32 d^2 per pass

    // ---- fused trivial fills (independent of KNN) ----
    if (j < AA)  out[blk * AA + j]  = (float)blk;   // block_id
    if (j == AA) out[O_BATCH + blk] = (float)b;     // batch_id
    {
        int idx = blk * 288 + j;                    // 288 attr elems / block
        int e = idx >> 4, col = idx & 15;
        out[O_ATTR + idx] = emb[(e < NE_HALF ? 0 : 16) + col];
        if (j < 32) {
            int idx2 = idx + 256;
            int e2 = idx2 >> 4, col2 = idx2 & 15;
            out[O_ATTR + idx2] = emb[(e2 < NE_HALF ? 0 : 16) + col2];
        }
    }

    // ---- stage row-i atoms; init ----
    if (j < 45)  sAi[j] = pos[(size_t)blk * 45 + j];
    if (j == 255) sCnt = 0;
    sD64[j] = INFINITY;
    __syncthreads();
    if (j < AA) {
        float x0 = sAi[3*j], x1 = sAi[3*j+1], x2 = sAi[3*j+2];
        sX2i[j] = x0*x0 + x1*x1 + x2*x2;
    }

    // thread-private atoms of candidate block j (f32)
    float xj[AA][3], x2j[AA];
    const float* pj = pos + (size_t)(b * LL + j) * 45;
    #pragma unroll
    for (int c = 0; c < AA; ++c) {
        xj[c][0] = pj[3*c]; xj[c][1] = pj[3*c+1]; xj[c][2] = pj[3*c+2];
        x2j[c] = xj[c][0]*xj[c][0] + xj[c][1]*xj[c][1] + xj[c][2]*xj[c][2];
    }
    int ft = frag[b * LL + j];
    sSeg[j] = (ft == 2) ? 1 : ft;
    __syncthreads();

    // ---- phase 1: f32 min over 225 atom pairs (3 min accumulators) ----
    float m0 = INFINITY, m1 = INFINITY, m2 = INFINITY;
    for (int a = 0; a < AA; ++a) {
        float a0 = sAi[3*a], a1 = sAi[3*a+1], a2 = sAi[3*a+2];
        float x2a = sX2i[a];
        #pragma unroll
        for (int c = 0; c < AA; ++c) {
            float dot = fmaf(a0, xj[c][0], fmaf(a1, xj[c][1], a2 * xj[c][2]));
            float d2  = fmaf(-2.0f, dot, x2a + x2j[c]);
            if      (c % 3 == 0) m0 = fminf(m0, d2);
            else if (c % 3 == 1) m1 = fminf(m1, d2);
            else                 m2 = fminf(m2, d2);
        }
    }
    sD32[j] = fmaxf(fminf(m0, fminf(m1, m2)), 0.0f);
    __syncthreads();

    const int seg_i = sSeg[i];

    // ---- phase 2: wave0 finds the 9th-smallest f32 d^2 per pass ----
    if (j < 64) {
        for (int pass = 0; pass < 2; ++pass) {
            float dl[4]; int il[4];
            #pragma unroll
            for (int q = 0; q < 4; ++q) {
                int cand = j + (q << 6);
                bool ok = (pass == 0) ? (sSeg[cand] == seg_i && cand != i)
                                      : (sSeg[cand] != seg_i);
                dl[q] = ok ? sD32[cand] : INFINITY;
                il[q] = cand;
            }
            float v9 = INFINITY;
            for (int k = 0; k < KK; ++k) {
                float v = dl[0]; int id = il[0];
                #pragma unroll
                for (int q = 1; q < 4; ++q)
                    if (dl[q] < v || (dl[q] == v && il[q] < id)) { v = dl[q]; id = il[q]; }
                for (int off = 1; off < 64; off <<= 1) {
                    float ov = __shfl_xor(v, off, 64);
                    int   oi = __shfl_xor(id, off, 64);
                    if (ov < v || (ov == v && oi < id)) { v = ov; id = oi; }
                }
                if ((id & 63) == j) dl[id >> 6] = INFINITY;   // remove winner
                v9 = v;
            }
            if (j == 0) sV9[pass] = v9;
        }
    }
    __syncthreads();

    // ---- phase 3: mark candidates near/inside the top-9 boundary ----
    {
        bool okI = (sSeg[j] == seg_i) && (j != i);
        bool okX = (sSeg[j] != seg_i);
        float dj = sD32[j];
        bool mark = (okI && dj <= sV9[0] + DELTA) ||
                    (okX && dj <= sV9[1] + DELTA);
        if (mark) { int p = atomicAdd(&sCnt, 1); sList[p] = j; }
    }
    __syncthreads();
    const int cnt = sCnt;   // >= 18 (intra top-9 and inter top-9 disjoint)

    // ---- phase 4: cooperative f64 refine of marked candidates ----
    // one candidate per wave; 64 lanes split the 225 atom pairs.
    {
        const int wv = j >> 6, lane = j & 63;
        for (int base = 0; base < cnt; base += 4) {
            int k = base + wv;
            double dmin = INFINITY;
            int cand = 0;
            if (k < cnt) {
                cand = sList[k];
                const float* pc = pos + (size_t)(b * LL + cand) * 45;
                for (int p = lane; p < 225; p += 64) {
                    int a = p / 15, c = p - a * 15;
                    double ax = (double)sAi[3*a], ay = (double)sAi[3*a+1],
                           az = (double)sAi[3*a+2];
                    double cx = (double)pc[3*c], cy = (double)pc[3*c+1],
                           cz = (double)pc[3*c+2];
                    double dot = ax*cx + ay*cy + az*cz;
                    double d2  = (ax*ax + ay*ay + az*az)
                               + (cx*cx + cy*cy + cz*cz) - 2.0 * dot;
                    dmin = fmin(dmin, d2);
                }
            }
            #pragma unroll
            for (int off = 1; off < 64; off <<= 1)
                dmin = fmin(dmin, __shfl_xor(dmin, off, 64));
            if (lane == 0 && k < cnt) sD64[cand] = fmax(dmin, 0.0);
        }
    }
    __syncthreads();

    // ---- phase 5: wave0 ordered top-9 selection on f64 (as round 4) ----
    if (j < 64) {
        const int row = blk;
        for (int pass = 0; pass < 2; ++pass) {
            double dl[4]; int il[4];
            #pragma unroll
            for (int q = 0; q < 4; ++q) {
                int cand = j + (q << 6);
                bool ok = (pass == 0) ? (sSeg[cand] == seg_i && cand != i)
                                      : (sSeg[cand] != seg_i);
                dl[q] = ok ? sD64[cand] : INFINITY;   // unmarked => INF
                il[q] = cand;
            }
            for (int k = 0; k < KK; ++k) {
                double v = dl[0]; int id = il[0];
                #pragma unroll
                for (int q = 1; q < 4; ++q)
                    if (dl[q] < v || (dl[q] == v && il[q] < id)) { v = dl[q]; id = il[q]; }
                for (int off = 1; off < 64; off <<= 1) {
                    double ov = __shfl_xor(v, off, 64);
                    int    oi = __shfl_xor(id, off, 64);
                    if (ov < v || (ov == v && oi < id)) { v = ov; id = oi; }
                }
                if ((id & 63) == j) dl[id >> 6] = INFINITY;   // remove winner
                if (j == 0) {
                    int e = (pass == 0 ? 0 : NE_HALF) + row * KK + k;
                    out[O_EDGES + e]      = (float)row;             // src
                    out[O_EDGES + NE + e] = (float)(b * LL + id);   // dst
                }
            }
        }
    }
}

extern "C" void kernel_launch(void* const* d_in, const int* in_sizes, int n_in,
                              void* d_out, int out_size, void* d_ws, size_t ws_size,
                              hipStream_t stream) {
    const float* pos  = (const float*)d_in[0];   // pos_heavyatom [8,256,15,3] f32
    const int*   frag = (const int*)d_in[6];     // fragment_type [8,256] i32
    const float* emb  = (const float*)d_in[7];   // edge_emb [2,16] f32
    float* out = (float*)d_out;

    edge_fused_kernel<<<dim3(BB * LL), dim3(256), 0, stream>>>(pos, frag, emb, out);
}

// Round 6
// 128.924 us; speedup vs baseline: 1.0243x; 1.0243x over previous
//
#include <hip/hip_runtime.h>

// EdgeEmbedding: B=8, L=256, A=15, K=9, EDGE_SIZE=16 — single fused kernel.
//
// Output layout (all float32, concatenated flat):
//   [0,      30720)  block_id   = i/15
//   [30720,  32768)  batch_id   = i/256
//   [32768, 106496)  edges [2][36864]   (row0 src, row1 dst; intra then inter)
//   [106496,696320)  edge_attr [36864][16]
//
// Algorithm (round-5 post-mortem: serial wave0 butterfly selection + compiler
// demoting the 45-float candidate array were the bottleneck):
//   1. f32 min-d^2 per candidate, 3 chunks x 5 candidate atoms (register-
//      resident), row-i atoms as float4{x,y,z,x2} in LDS.
//   2. RANK-BY-COUNTING: every thread counts same-class lex-smaller keys over
//      all 256 (uint4 LDS broadcast reads) -> exact f32 rank, fully parallel.
//      Rank-8 thread per class publishes v9.
//   3. Mark d32 <= v9 + DELTA (DELTA=0.02 >> 40x f32 error => f64 top-9 is
//      provably a subset of marked).
//   4. f64 refine of marked candidates only (one candidate per wave, lanes
//      split the 225 atom pairs, shuffle-min reduce).
//   5. f64 rank among marked -> winners write their own ordered edge slots.
// f64 ordering identical to the all-f64 round-4 kernel (absmax 37, passed).

#define BB   8
#define LL   256
#define AA   15
#define KK   9

#define O_BATCH   30720
#define O_EDGES   32768
#define NE_HALF   18432   // B*L*K
#define NE        36864
#define O_ATTR    106496
#define DELTA     0.02f

__global__ __launch_bounds__(256) void edge_fused_kernel(
    const float* __restrict__ pos,   // [B,L,A,3] f32
    const int*   __restrict__ frag,  // [B,L]
    const float* __restrict__ emb,   // [2,16]
    float*       __restrict__ out)
{
    const int blk = blockIdx.x;      // = b*256 + i
    const int b   = blk >> 8;
    const int i   = blk & 255;
    const int j   = threadIdx.x;     // candidate dst block

    __shared__ float4 sAi4[AA];                       // row-i: x,y,z,|x|^2
    __shared__ double dAi[AA * 3];                    // row-i coords (f64)
    __shared__ double dX2i[AA];                       // row-i |x|^2 (f64)
    __shared__ __align__(16) unsigned int sKey[LL];   // (bits(d32)<<1)|seg
    __shared__ double sD64[LL];                       // refined f64 d^2
    __shared__ int    sList[LL];                      // marked candidates
    __shared__ int    sCnt;
    __shared__ float  sV9[2];                         // f32 rank-8 value/class

    // ---- fused trivial fills (independent of everything) ----
    if (j < AA)  out[blk * AA + j]  = (float)blk;     // block_id
    if (j == AA) out[O_BATCH + blk] = (float)b;       // batch_id
    {
        int idx = blk * 288 + j;                      // 288 attr elems/block
        out[O_ATTR + idx] = emb[(((idx >> 4) < NE_HALF) ? 0 : 16) + (idx & 15)];
        if (j < 32) {
            int idx2 = idx + 256;
            out[O_ATTR + idx2] = emb[(((idx2 >> 4) < NE_HALF) ? 0 : 16) + (idx2 & 15)];
        }
    }

    // ---- stage row-i atoms (f32 packed + f64), init ----
    if (j < AA) {
        const float* p = pos + (size_t)blk * 45 + j * 3;
        float x = p[0], y = p[1], z = p[2];
        sAi4[j] = make_float4(x, y, z, x*x + y*y + z*z);
        double dx = (double)x, dy = (double)y, dz = (double)z;
        dAi[3*j] = dx; dAi[3*j+1] = dy; dAi[3*j+2] = dz;
        dX2i[j] = dx*dx + dy*dy + dz*dz;
    }
    if (j == 255) { sCnt = 0; sV9[0] = INFINITY; sV9[1] = INFINITY; }
    sD64[j] = INFINITY;

    const int ftj  = frag[b * LL + j];
    const int segj = (ftj == 2) ? 1 : ftj;
    const int fti  = frag[blk];                       // uniform -> s_load
    const int segi = (fti == 2) ? 1 : fti;
    __syncthreads();

    // ---- phase 1: f32 min d^2, 3 chunks of 5 candidate atoms ----
    const float* pj = pos + (size_t)(b * LL + j) * 45;
    float mn0 = INFINITY, mn1 = INFINITY, mn2 = INFINITY;
    for (int cb = 0; cb < AA; cb += 5) {
        float cx[5], cy[5], cz[5], c2[5];
        #pragma unroll
        for (int q = 0; q < 5; ++q) {
            cx[q] = pj[3*(cb+q) + 0];
            cy[q] = pj[3*(cb+q) + 1];
            cz[q] = pj[3*(cb+q) + 2];
            c2[q] = cx[q]*cx[q] + cy[q]*cy[q] + cz[q]*cz[q];
        }
        #pragma unroll 5
        for (int a = 0; a < AA; ++a) {
            float4 A = sAi4[a];
            #pragma unroll
            for (int q = 0; q < 5; ++q) {
                float dot = fmaf(A.x, cx[q], fmaf(A.y, cy[q], A.z * cz[q]));
                float d2  = fmaf(-2.0f, dot, A.w + c2[q]);
                if      (q == 0 || q == 3) mn0 = fminf(mn0, d2);
                else if (q == 1 || q == 4) mn1 = fminf(mn1, d2);
                else                       mn2 = fminf(mn2, d2);
            }
        }
    }
    const float d32 = fmaxf(fminf(mn0, fminf(mn1, mn2)), 0.0f);
    const unsigned int key_j = (__float_as_uint(d32) << 1) | (unsigned)segj;
    sKey[j] = key_j;
    __syncthreads();

    // ---- phase 2: exact f32 rank by counting (parallel, all threads) ----
    // class: 0 = intra (seg==segi, j!=i), 1 = inter (seg!=segi), -1 = self
    const int cls = (j == i) ? -1 : ((segj == segi) ? 0 : 1);
    int rank = 0;
    {
        const uint4* k4 = (const uint4*)sKey;
        for (int t = 0; t < 64; ++t) {
            uint4 kk = k4[t];
            int base = t << 2;
            #pragma unroll
            for (int q = 0; q < 4; ++q) {
                unsigned kx = (q == 0) ? kk.x : (q == 1) ? kk.y
                            : (q == 2) ? kk.z : kk.w;
                int k = base + q;
                bool same = ((kx ^ key_j) & 1u) == 0u;       // same seg/class
                bool lt   = (kx < key_j) || (kx == key_j && k < j);
                rank += (same && k != i && lt) ? 1 : 0;
            }
        }
    }
    if (rank == 8 && cls == 0) sV9[0] = d32;   // exactly one per class
    if (rank == 8 && cls == 1) sV9[1] = d32;
    __syncthreads();

    // ---- phase 3: mark boundary superset ----
    const bool marked = (cls >= 0) && (d32 <= sV9[cls] + DELTA);
    if (marked) { int p = atomicAdd(&sCnt, 1); sList[p] = j; }
    __syncthreads();
    const int cnt = sCnt;   // ~18-25

    // ---- phase 4: f64 refine of marked (wave per candidate) ----
    {
        const int wv = j >> 6, lane = j & 63;
        for (int base = 0; base < cnt; base += 4) {
            int t = base + wv;
            double dmin = INFINITY;
            int cand = -1;
            if (t < cnt) {
                cand = sList[t];
                const float* pc = pos + (size_t)(b * LL + cand) * 45;
                for (int p = lane; p < 225; p += 64) {
                    int a = p / 15, c = p - a * 15;
                    double cx = (double)pc[3*c], cy = (double)pc[3*c+1],
                           cz = (double)pc[3*c+2];
                    double dot = dAi[3*a]*cx + dAi[3*a+1]*cy + dAi[3*a+2]*cz;
                    double c2  = cx*cx + cy*cy + cz*cz;
                    double d2  = (dX2i[a] + c2) - 2.0 * dot;
                    dmin = fmin(dmin, d2);
                }
            }
            #pragma unroll
            for (int off = 1; off < 64; off <<= 1)
                dmin = fmin(dmin, __shfl_xor(dmin, off, 64));
            if (lane == 0 && t < cnt) sD64[cand] = fmax(dmin, 0.0);
        }
    }
    __syncthreads();

    // ---- phase 5: f64 rank among marked; winners write ordered slots ----
    if (marked) {
        double dj = sD64[j];
        int r = 0;
        for (int t = 0; t < cnt; ++t) {
            int cand = sList[t];
            if (((sKey[cand] ^ key_j) & 1u) == 0u) {   // same class
                double dc = sD64[cand];
                if (dc < dj || (dc == dj && cand < j)) ++r;
            }
        }
        if (r < KK) {
            int e = (cls == 0 ? 0 : NE_HALF) + blk * KK + r;
            out[O_EDGES + e]      = (float)blk;             // src
            out[O_EDGES + NE + e] = (float)(b * LL + j);    // dst
        }
    }
}

extern "C" void kernel_launch(void* const* d_in, const int* in_sizes, int n_in,
                              void* d_out, int out_size, void* d_ws, size_t ws_size,
                              hipStream_t stream) {
    const float* pos  = (const float*)d_in[0];   // pos_heavyatom [8,256,15,3] f32
    const int*   frag = (const int*)d_in[6];     // fragment_type [8,256] i32
    const float* emb  = (const float*)d_in[7];   // edge_emb [2,16] f32
    float* out = (float*)d_out;

    edge_fused_kernel<<<dim3(BB * LL), dim3(256), 0, stream>>>(pos, frag, emb, out);
}

// Round 7
// 105.245 us; speedup vs baseline: 1.2548x; 1.2250x over previous
//
#include <hip/hip_runtime.h>

// EdgeEmbedding: B=8, L=256, A=15, K=9, EDGE_SIZE=16 — single fused kernel.
//
// Output layout (all float32, concatenated flat):
//   [0,      30720)  block_id   = i/15
//   [30720,  32768)  batch_id   = i/256
//   [32768, 106496)  edges [2][36864]   (row0 src, row1 dst; intra then inter)
//   [106496,696320)  edge_attr [36864][16]
//
// Algorithm (round-6 post-mortem: exact rank-by-counting was ~1900 VALU/thread,
// 1.6x the distance math — replaced by a histogram quantile, ~50 ops):
//   1. f32 min-d^2 per candidate block (225 atom pairs, register-resident
//      candidate atoms, row-i atoms as float4{x,y,z,x2} in LDS).
//   2. Histogram on bits(d32)>>21 (monotone, 4 bins/octave), 128 bins x
//      2 classes, LDS atomicAdd. Waves 0/1: 64-lane inclusive scan (2 bins
//      per lane), ballot+ctz -> first bin where cum >= 9; publish t = bin
//      UPPER edge (so >= true f32 9th value).
//   3. Mark d32 <= t + DELTA (DELTA=0.02 >> 40x f32 error; t >= v9 => marked
//      set provably contains the f64 top-9 per class). cnt ~ 24-28.
//   4. f64 refine of marked candidates only (wave per candidate, 64 lanes
//      split the 225 atom pairs, shuffle-min reduce).
//   5. f64 rank among same-class marked -> winners write their own ordered
//      edge slots. f64 ordering identical to round-4's all-f64 kernel.

#define BB   8
#define LL   256
#define AA   15
#define KK   9

#define O_BATCH   30720
#define O_EDGES   32768
#define NE_HALF   18432   // B*L*K
#define NE        36864
#define O_ATTR    106496
#define DELTA     0.02f
#define HBASE     448     // bits>>21 of 0x38000000 (3.05e-5); 128 bins up to 131072

__global__ __launch_bounds__(256) void edge_fused_kernel(
    const float* __restrict__ pos,   // [B,L,A,3] f32
    const int*   __restrict__ frag,  // [B,L]
    const float* __restrict__ emb,   // [2,16]
    float*       __restrict__ out)
{
    const int blk = blockIdx.x;      // = b*256 + i
    const int b   = blk >> 8;
    const int i   = blk & 255;
    const int j   = threadIdx.x;     // candidate dst block

    __shared__ float4 sAi4[AA];      // row-i: x,y,z,|x|^2
    __shared__ double dAi[AA * 3];   // row-i coords (f64)
    __shared__ double dX2i[AA];      // row-i |x|^2 (f64)
    __shared__ double sD64[LL];      // refined f64 d^2 (marked only)
    __shared__ int    sList[LL];     // (cand<<1)|class
    __shared__ int    sHist[2*128];  // per-class histogram
    __shared__ float  sT[2];         // per-class marking threshold
    __shared__ int    sCnt;

    // ---- fused trivial fills (independent of everything) ----
    if (j < AA)  out[blk * AA + j]  = (float)blk;     // block_id
    if (j == AA) out[O_BATCH + blk] = (float)b;       // batch_id
    {
        int idx = blk * 288 + j;                      // 288 attr elems/block
        out[O_ATTR + idx] = emb[(((idx >> 4) < NE_HALF) ? 0 : 16) + (idx & 15)];
        if (j < 32) {
            int idx2 = idx + 256;
            out[O_ATTR + idx2] = emb[(((idx2 >> 4) < NE_HALF) ? 0 : 16) + (idx2 & 15)];
        }
    }

    // ---- stage row-i atoms (f32 packed + f64); zero hist/cnt ----
    if (j < AA) {
        const float* p = pos + (size_t)blk * 45 + j * 3;
        float x = p[0], y = p[1], z = p[2];
        sAi4[j] = make_float4(x, y, z, x*x + y*y + z*z);
        double dx = (double)x, dy = (double)y, dz = (double)z;
        dAi[3*j] = dx; dAi[3*j+1] = dy; dAi[3*j+2] = dz;
        dX2i[j] = dx*dx + dy*dy + dz*dz;
    }
    sHist[j] = 0;
    if (j == 255) sCnt = 0;

    const int ftj  = frag[b * LL + j];
    const int segj = (ftj == 2) ? 1 : ftj;
    const int fti  = frag[blk];                       // uniform -> s_load
    const int segi = (fti == 2) ? 1 : fti;
    // class: 0 = intra (seg==segi, j!=i), 1 = inter, -1 = self
    const int cls  = (j == i) ? -1 : ((segj == segi) ? 0 : 1);
    __syncthreads();

    // ---- phase 1: f32 min d^2, 3 chunks of 5 candidate atoms ----
    // restructure: m[q] = min_a(x2a - 2*dot); d2_q = m[q] + c2[q] afterwards
    const float* pj = pos + (size_t)(b * LL + j) * 45;
    float d32 = INFINITY;
    for (int cb = 0; cb < AA; cb += 5) {
        float cx[5], cy[5], cz[5], c2[5], m[5];
        #pragma unroll
        for (int q = 0; q < 5; ++q) {
            cx[q] = pj[3*(cb+q) + 0];
            cy[q] = pj[3*(cb+q) + 1];
            cz[q] = pj[3*(cb+q) + 2];
            c2[q] = cx[q]*cx[q] + cy[q]*cy[q] + cz[q]*cz[q];
            m[q]  = INFINITY;
        }
        #pragma unroll 5
        for (int a = 0; a < AA; ++a) {
            float4 A = sAi4[a];
            #pragma unroll
            for (int q = 0; q < 5; ++q) {
                float dot = fmaf(A.x, cx[q], fmaf(A.y, cy[q], A.z * cz[q]));
                m[q] = fminf(m[q], fmaf(-2.0f, dot, A.w));
            }
        }
        #pragma unroll
        for (int q = 0; q < 5; ++q)
            d32 = fminf(d32, m[q] + c2[q]);
    }
    d32 = fmaxf(d32, 0.0f);

    // ---- phase 2a: histogram (bits>>21 is monotone for d32 >= 0) ----
    if (cls >= 0) {
        int bin = (int)(__float_as_uint(d32) >> 21) - HBASE;
        bin = min(127, max(0, bin));
        atomicAdd(&sHist[cls * 128 + bin], 1);
    }
    __syncthreads();

    // ---- phase 2b: waves 0/1 find crossing bin, publish upper edge ----
    if (j < 128) {
        const int lane = j & 63, cw = j >> 6;
        int c0 = sHist[cw * 128 + 2*lane];
        int c1 = sHist[cw * 128 + 2*lane + 1];
        int s  = c0 + c1;
        int cum = s;
        #pragma unroll
        for (int off = 1; off < 64; off <<= 1) {
            int v = __shfl_up(cum, off, 64);
            if (lane >= off) cum += v;
        }
        unsigned long long msk = __ballot(cum >= KK);   // nonzero: >=127/class
        int f = __builtin_ctzll(msk);
        if (lane == f) {
            int before = cum - s;
            int bin = (before + c0 >= KK) ? 2*f : 2*f + 1;
            sT[cw] = (bin >= 127) ? INFINITY
                   : __uint_as_float((unsigned)(HBASE + bin + 1) << 21);
        }
    }
    __syncthreads();

    // ---- phase 3: mark refine superset ----
    const bool marked = (cls >= 0) && (d32 <= sT[cls] + DELTA);
    if (marked) { int p = atomicAdd(&sCnt, 1); sList[p] = (j << 1) | cls; }
    __syncthreads();
    const int cnt = sCnt;   // ~24-28

    // ---- phase 4: f64 refine of marked (wave per candidate) ----
    {
        const int wv = j >> 6, lane = j & 63;
        for (int base = 0; base < cnt; base += 4) {
            int t = base + wv;
            double dmin = INFINITY;
            int cand = -1;
            if (t < cnt) {
                cand = sList[t] >> 1;
                const float* pc = pos + (size_t)(b * LL + cand) * 45;
                for (int p = lane; p < 225; p += 64) {
                    int a = p / 15, c = p - a * 15;
                    double cx = (double)pc[3*c], cy = (double)pc[3*c+1],
                           cz = (double)pc[3*c+2];
                    double dot = dAi[3*a]*cx + dAi[3*a+1]*cy + dAi[3*a+2]*cz;
                    double c2  = cx*cx + cy*cy + cz*cz;
                    double d2  = (dX2i[a] + c2) - 2.0 * dot;
                    dmin = fmin(dmin, d2);
                }
            }
            #pragma unroll
            for (int off = 1; off < 64; off <<= 1)
                dmin = fmin(dmin, __shfl_xor(dmin, off, 64));
            if (lane == 0 && t < cnt) sD64[cand] = fmax(dmin, 0.0);
        }
    }
    __syncthreads();

    // ---- phase 5: f64 rank among same-class marked; winners write ----
    if (marked) {
        double dj = sD64[j];
        int r = 0;
        for (int t = 0; t < cnt; ++t) {
            int e = sList[t];
            if ((e & 1) == cls) {
                int cand = e >> 1;
                double dc = sD64[cand];
                if (dc < dj || (dc == dj && cand < j)) ++r;
            }
        }
        if (r < KK) {
            int e = (cls == 0 ? 0 : NE_HALF) + blk * KK + r;
            out[O_EDGES + e]      = (float)blk;             // src
            out[O_EDGES + NE + e] = (float)(b * LL + j);    // dst
        }
    }
}

extern "C" void kernel_launch(void* const* d_in, const int* in_sizes, int n_in,
                              void* d_out, int out_size, void* d_ws, size_t ws_size,
                              hipStream_t stream) {
    const float* pos  = (const float*)d_in[0];   // pos_heavyatom [8,256,15,3] f32
    const int*   frag = (const int*)d_in[6];     // fragment_type [8,256] i32
    const float* emb  = (const float*)d_in[7];   // edge_emb [2,16] f32
    float* out = (float*)d_out;

    edge_fused_kernel<<<dim3(BB * LL), dim3(256), 0, stream>>>(pos, frag, emb, out);
}

// Round 8
// 97.309 us; speedup vs baseline: 1.3571x; 1.0816x over previous
//
#include <hip/hip_runtime.h>

// EdgeEmbedding: B=8, L=256, A=15, K=9, EDGE_SIZE=16 — single fused kernel.
//
// Output layout (all float32, concatenated flat):
//   [0,      30720)  block_id   = i/15
//   [30720,  32768)  batch_id   = i/256
//   [32768, 106496)  edges [2][36864]   (row0 src, row1 dst; intra then inter)
//   [106496,696320)  edge_attr [36864][16]
//
// Round-8 changes (round-7 post-mortem: phase 4 f64 cost == phase 1 cost):
//   1. f32 min-d^2: row-i atoms packed {-2x,-2y,-2z,x2} -> 4 VALU/pair
//      (3 fma + fmin), +c2 hoisted out of the a-loop.
//   2. Histogram quantile at bits>>19 (512 bins, 4.4% steps) -> marked
//      cnt ~19 instead of ~26. T = upper edge of crossing bin >= v9;
//      mark d32 <= T + DELTA (DELTA = 5e-3 >= 16x the 3e-4 f32 error
//      bound => f64 top-9 provably subset of marked).
//   3. f64 refine with per-pair f32 prefilter: wave recomputes its pairs
//      in f32 and runs f64 ONLY on pairs with d2f32 <= sD32[cand] + EPS
//      (EPS = 1e-2 >= 2x error bound => true argmin pair included; extra
//      pairs can only match the min). f64 values bit-identical to round 4.
//   4. f64 rank among same-class marked -> winners write ordered slots.

#define BB   8
#define LL   256
#define AA   15
#define KK   9

#define O_BATCH   30720
#define O_EDGES   32768
#define NE_HALF   18432   // B*L*K
#define NE        36864
#define O_ATTR    106496
#define DELTA     0.005f
#define EPS_PAIR  0.01f
#define HBASE     1904    // (0x3B800000 >> 19): bins start at 2^-8
#define NBIN      512

__global__ __launch_bounds__(256) void edge_fused_kernel(
    const float* __restrict__ pos,   // [B,L,A,3] f32
    const int*   __restrict__ frag,  // [B,L]
    const float* __restrict__ emb,   // [2,16]
    float*       __restrict__ out)
{
    const int blk = blockIdx.x;      // = b*256 + i
    const int b   = blk >> 8;
    const int i   = blk & 255;
    const int j   = threadIdx.x;     // candidate dst block

    __shared__ float4 sAi4[AA];      // row-i: {-2x, -2y, -2z, |x|^2}
    __shared__ double dAi[AA * 3];   // row-i coords (f64)
    __shared__ double dX2i[AA];      // row-i |x|^2 (f64)
    __shared__ float  sD32[LL];      // f32 min d^2 per candidate
    __shared__ double sD64[LL];      // refined f64 d^2 (marked only)
    __shared__ int    sList[LL];     // (cand<<1)|class
    __shared__ int    sHist[2*NBIN]; // per-class histogram
    __shared__ float  sT[2];         // per-class marking threshold
    __shared__ int    sCnt;

    // ---- fused trivial fills (independent of everything) ----
    if (j < AA)  out[blk * AA + j]  = (float)blk;     // block_id
    if (j == AA) out[O_BATCH + blk] = (float)b;       // batch_id
    {
        int idx = blk * 288 + j;                      // 288 attr elems/block
        out[O_ATTR + idx] = emb[(((idx >> 4) < NE_HALF) ? 0 : 16) + (idx & 15)];
        if (j < 32) {
            int idx2 = idx + 256;
            out[O_ATTR + idx2] = emb[(((idx2 >> 4) < NE_HALF) ? 0 : 16) + (idx2 & 15)];
        }
    }

    // ---- stage row-i atoms; zero hist/cnt; init sD64 ----
    if (j < AA) {
        const float* p = pos + (size_t)blk * 45 + j * 3;
        float x = p[0], y = p[1], z = p[2];
        sAi4[j] = make_float4(-2.0f * x, -2.0f * y, -2.0f * z,
                              x*x + y*y + z*z);
        double dx = (double)x, dy = (double)y, dz = (double)z;
        dAi[3*j] = dx; dAi[3*j+1] = dy; dAi[3*j+2] = dz;
        dX2i[j] = dx*dx + dy*dy + dz*dz;
    }
    #pragma unroll
    for (int q = 0; q < 4; ++q) sHist[j + (q << 8)] = 0;   // 1024 ints
    if (j == 255) sCnt = 0;
    sD64[j] = INFINITY;

    const int ftj  = frag[b * LL + j];
    const int segj = (ftj == 2) ? 1 : ftj;
    const int fti  = frag[blk];                       // uniform
    const int segi = (fti == 2) ? 1 : fti;
    // class: 0 = intra (seg==segi, j!=i), 1 = inter, -1 = self
    const int cls  = (j == i) ? -1 : ((segj == segi) ? 0 : 1);
    __syncthreads();

    // ---- phase 1: f32 min d^2, 3 chunks of 5 candidate atoms ----
    // inner pair: dot' = fma(-2ax,cx, fma(-2ay,cy, fma(-2az,cz, x2a)))
    //             m[q] = fmin(m[q], dot');  d2 = m[q] + c2[q] after a-loop
    const float* pj = pos + (size_t)(b * LL + j) * 45;
    float d32 = INFINITY;
    for (int cb = 0; cb < AA; cb += 5) {
        float cx[5], cy[5], cz[5], c2[5], m[5];
        #pragma unroll
        for (int q = 0; q < 5; ++q) {
            cx[q] = pj[3*(cb+q) + 0];
            cy[q] = pj[3*(cb+q) + 1];
            cz[q] = pj[3*(cb+q) + 2];
            c2[q] = cx[q]*cx[q] + cy[q]*cy[q] + cz[q]*cz[q];
            m[q]  = INFINITY;
        }
        #pragma unroll 5
        for (int a = 0; a < AA; ++a) {
            float4 A = sAi4[a];
            #pragma unroll
            for (int q = 0; q < 5; ++q) {
                float dp = fmaf(A.x, cx[q], fmaf(A.y, cy[q],
                            fmaf(A.z, cz[q], A.w)));
                m[q] = fminf(m[q], dp);
            }
        }
        #pragma unroll
        for (int q = 0; q < 5; ++q)
            d32 = fminf(d32, m[q] + c2[q]);
    }
    d32 = fmaxf(d32, 0.0f);
    sD32[j] = d32;

    // ---- phase 2a: histogram (bits>>19 monotone for d32 >= 0) ----
    if (cls >= 0) {
        int bin = (int)(__float_as_uint(d32) >> 19) - HBASE;
        bin = min(NBIN - 1, max(0, bin));
        atomicAdd(&sHist[cls * NBIN + bin], 1);
    }
    __syncthreads();

    // ---- phase 2b: waves 0/1 scan 512 bins (8/lane), publish threshold ----
    if (j < 128) {
        const int lane = j & 63, cw = j >> 6;
        int c[8], s = 0;
        #pragma unroll
        for (int q = 0; q < 8; ++q) {
            c[q] = sHist[cw * NBIN + 8*lane + q];
            s += c[q];
        }
        int cum = s;
        #pragma unroll
        for (int off = 1; off < 64; off <<= 1) {
            int v = __shfl_up(cum, off, 64);
            if (lane >= off) cum += v;
        }
        unsigned long long msk = __ballot(cum >= KK);
        if (msk == 0ull) {                 // degenerate (<9 in class)
            if (lane == 0) sT[cw] = INFINITY;
        } else {
            int f = __builtin_ctzll(msk);
            if (lane == f) {
                int before = cum - s;
                int bin = -1;
                #pragma unroll
                for (int q = 0; q < 8; ++q) {
                    before += c[q];
                    if (bin < 0 && before >= KK) bin = 8*f + q;
                }
                sT[cw] = (bin >= NBIN - 1) ? INFINITY
                       : __uint_as_float((unsigned)(HBASE + bin + 1) << 19);
            }
        }
    }
    __syncthreads();

    // ---- phase 3: mark refine superset ----
    const bool marked = (cls >= 0) && (d32 <= sT[cls] + DELTA);
    if (marked) { int p = atomicAdd(&sCnt, 1); sList[p] = (j << 1) | cls; }
    __syncthreads();
    const int cnt = sCnt;   // ~18-22

    // ---- phase 4: f64 refine of marked (wave/candidate, f32 prefilter) ----
    {
        const int wv = j >> 6, lane = j & 63;
        for (int base = 0; base < cnt; base += 4) {
            int t = base + wv;
            double dmin = INFINITY;
            int cand = -1;
            if (t < cnt) {
                cand = sList[t] >> 1;
                const float thr = sD32[cand] + EPS_PAIR;
                const float* pc = pos + (size_t)(b * LL + cand) * 45;
                #pragma unroll
                for (int s4 = 0; s4 < 4; ++s4) {
                    int p = lane + (s4 << 6);
                    if (p < 225) {
                        int a = p / 15, c = p - a * 15;
                        float cx = pc[3*c], cy = pc[3*c+1], cz = pc[3*c+2];
                        float4 A = sAi4[a];
                        float c2 = cx*cx + cy*cy + cz*cz;
                        float dp = fmaf(A.x, cx, fmaf(A.y, cy,
                                    fmaf(A.z, cz, A.w)));
                        if (dp + c2 <= thr) {          // f64 only near the min
                            double dcx = (double)cx, dcy = (double)cy,
                                   dcz = (double)cz;
                            double dot = dAi[3*a]*dcx + dAi[3*a+1]*dcy
                                       + dAi[3*a+2]*dcz;
                            double d2 = (dX2i[a]
                                       + (dcx*dcx + dcy*dcy + dcz*dcz))
                                       - 2.0 * dot;
                            dmin = fmin(dmin, d2);
                        }
                    }
                }
            }
            #pragma unroll
            for (int off = 1; off < 64; off <<= 1)
                dmin = fmin(dmin, __shfl_xor(dmin, off, 64));
            if (lane == 0 && t < cnt) sD64[cand] = fmax(dmin, 0.0);
        }
    }
    __syncthreads();

    // ---- phase 5: f64 rank among same-class marked; winners write ----
    if (marked) {
        double dj = sD64[j];
        int r = 0;
        for (int t = 0; t < cnt; ++t) {
            int e = sList[t];
            if ((e & 1) == cls) {
                int cand = e >> 1;
                double dc = sD64[cand];
                if (dc < dj || (dc == dj && cand < j)) ++r;
            }
        }
        if (r < KK) {
            int e = (cls == 0 ? 0 : NE_HALF) + blk * KK + r;
            out[O_EDGES + e]      = (float)blk;             // src
            out[O_EDGES + NE + e] = (float)(b * LL + j);    // dst
        }
    }
}

extern "C" void kernel_launch(void* const* d_in, const int* in_sizes, int n_in,
                              void* d_out, int out_size, void* d_ws, size_t ws_size,
                              hipStream_t stream) {
    const float* pos  = (const float*)d_in[0];   // pos_heavyatom [8,256,15,3] f32
    const int*   frag = (const int*)d_in[6];     // fragment_type [8,256] i32
    const float* emb  = (const float*)d_in[7];   // edge_emb [2,16] f32
    float* out = (float*)d_out;

    edge_fused_kernel<<<dim3(BB * LL), dim3(256), 0, stream>>>(pos, frag, emb, out);
}